// Round 4
// baseline (39.622 us; speedup 1.0000x reference)
//
#include <hip/hip_runtime.h>

typedef _Float16 f16x8  __attribute__((ext_vector_type(8)));
typedef float    f32x16 __attribute__((ext_vector_type(16)));

static constexpr int BATCH = 4;
static constexpr int NPTS  = 8192;
static constexpr int NPROB = 2 * BATCH;      // (batch, direction) = 8
static constexpr int TPB   = 256;            // 4 waves
static constexpr int WQ    = 32;             // queries per wave (MFMA cols)
static constexpr int QBLK  = (TPB / 64) * WQ;// 128 queries per block
static constexpr int NQB   = NPTS / QBLK;    // 64 query tiles
static constexpr int CHUNK = 1024;           // refs per LDS buffer
static constexpr int NCH   = NPTS / CHUNK;   // 8 chunks (full ref scan per block)

__device__ __forceinline__ unsigned packh2(_Float16 lo, _Float16 hi) {
    union { _Float16 h[2]; unsigned u; } v;
    v.h[0] = lo; v.h[1] = hi;
    return v.u;
}

// ---------------- main: inline f16 pack + full-ref MFMA NN + per-block sum ----------------
__global__ __launch_bounds__(TPB) void cd_main(const float* __restrict__ gen,
                                               const float* __restrict__ train,
                                               float* __restrict__ psum) {
    __shared__ uint4 rA[2][CHUNK];           // 32 KB double-buffered packed refs
    const int qb = blockIdx.x, prob = blockIdx.y;
    const int b = prob >> 1, dir = prob & 1;
    const float* qbase = (dir == 0 ? gen : train) + (size_t)b * NPTS * 3;
    const float* rbase = (dir == 0 ? train : gen) + (size_t)b * NPTS * 3;
    const int lane = threadIdx.x & 63, wave = threadIdx.x >> 6;

    // stage+pack one chunk: each thread loads 12 floats (4 points, float4-aligned),
    // rounds to f16, writes (-2x,-2y,-2z,yyhi,yylo,0,0,0) per point.
    auto stage = [&](int ch, int buf) {
        const float4* s4 = (const float4*)(rbase + ch * (CHUNK * 3)) + threadIdx.x * 3;
        const float4 v0 = s4[0], v1 = s4[1], v2 = s4[2];
        const float px[4] = {v0.x, v0.w, v1.z, v2.y};
        const float py[4] = {v0.y, v1.x, v1.w, v2.z};
        const float pz[4] = {v0.z, v1.y, v2.x, v2.w};
        #pragma unroll
        for (int i = 0; i < 4; ++i) {
            const _Float16 hx = (_Float16)px[i], hy = (_Float16)py[i], hz = (_Float16)pz[i];
            const float xr = (float)hx, yr = (float)hy, zr = (float)hz;   // exact
            const float yy = fmaf(xr, xr, fmaf(yr, yr, zr * zr));
            const _Float16 yh = (_Float16)yy;
            const _Float16 yl = (_Float16)(yy - (float)yh);               // hi/lo split
            rA[buf][threadIdx.x * 4 + i] =
                make_uint4(packh2((_Float16)(-2.0f * xr), (_Float16)(-2.0f * yr)),
                           packh2((_Float16)(-2.0f * zr), yh),
                           packh2(yl, (_Float16)0.0f), 0u);
        }
    };

    // query fragment: 32 queries per wave, k = [qx,qy,qz,1,1,0,0,0]; lanes>=32 zero
    const int qid = qb * QBLK + wave * WQ + (lane & 31);
    float qq = 0.0f;
    union { uint4 u; f16x8 h; } B;
    B.u = make_uint4(0u, 0u, 0u, 0u);
    if (lane < 32) {
        const float qx = qbase[qid*3+0], qy = qbase[qid*3+1], qz = qbase[qid*3+2];
        const _Float16 hx = (_Float16)qx, hy = (_Float16)qy, hz = (_Float16)qz;
        const float xr = (float)hx, yr = (float)hy, zr = (float)hz;
        qq  = fmaf(xr, xr, fmaf(yr, yr, zr * zr));
        B.u = make_uint4(packh2(hx, hy),
                         packh2(hz, (_Float16)0.0f) | 0x3C000000u,  // k3 = 1.0
                         0x3C00u, 0u);                               // k4 = 1.0
    }

    stage(0, 0);
    __syncthreads();

    float m = 3.4e38f;
    const int c = lane & 31;
    const f32x16 zc = {};
    for (int ch = 0; ch < NCH; ++ch) {
        if (ch + 1 < NCH) stage(ch + 1, (ch + 1) & 1);   // overlap next-chunk staging
        const uint4* buf = rA[ch & 1];
        #pragma unroll 8
        for (int t = 0; t < CHUNK / 32; ++t) {
            union { uint4 u; f16x8 h; } A;
            A.u = buf[t * 32 + c];
            f32x16 d = __builtin_amdgcn_mfma_f32_32x32x16_f16(A.h, B.h, zc, 0, 0, 0);
            m = fminf(fminf(d[0],  d[1]),  m);
            m = fminf(fminf(d[2],  d[3]),  m);
            m = fminf(fminf(d[4],  d[5]),  m);
            m = fminf(fminf(d[6],  d[7]),  m);
            m = fminf(fminf(d[8],  d[9]),  m);
            m = fminf(fminf(d[10], d[11]), m);
            m = fminf(fminf(d[12], d[13]), m);
            m = fminf(fminf(d[14], d[15]), m);
        }
        __syncthreads();
    }

    // fold the two 16-row halves; then deterministic fixed-tree sum over the block
    m = fminf(m, __shfl_xor(m, 32));
    float dq = 0.0f;
    if (lane < 32) dq = fmaxf(m + qq, 0.0f);
    #pragma unroll
    for (int off = 16; off >= 1; off >>= 1) dq += __shfl_xor(dq, off);
    __shared__ float wsum[4];
    if (lane == 0) wsum[wave] = dq;
    __syncthreads();
    if (threadIdx.x == 0)
        psum[prob * NQB + qb] = (wsum[0] + wsum[1]) + (wsum[2] + wsum[3]);
}

// ---------------- fin: deterministic sum of 512 block partials -> loss ----------------
__global__ void cd_fin(const float* __restrict__ psum, float* __restrict__ out) {
    float s = psum[threadIdx.x];             // 512 threads, one partial each
    #pragma unroll
    for (int off = 32; off >= 1; off >>= 1) s += __shfl_down(s, off, 64);
    __shared__ float p[8];
    if ((threadIdx.x & 63) == 0) p[threadIdx.x >> 6] = s;
    __syncthreads();
    if (threadIdx.x == 0) {
        float t = 0.0f;
        #pragma unroll
        for (int w = 0; w < 8; ++w) t += p[w];
        out[0] = t * (0.5f / BATCH);
    }
}

extern "C" void kernel_launch(void* const* d_in, const int* in_sizes, int n_in,
                              void* d_out, int out_size, void* d_ws, size_t ws_size,
                              hipStream_t stream) {
    const float* gen   = (const float*)d_in[0];   // [4,8192,3] f32
    const float* train = (const float*)d_in[1];   // [4,8192,3] f32
    float* psum = (float*)d_ws;                   // 512 floats (all written every call)
    float* out  = (float*)d_out;

    cd_main<<<dim3(NQB, NPROB), TPB, 0, stream>>>(gen, train, psum);
    cd_fin<<<1, NQB * NPROB, 0, stream>>>(psum, out);
}

// Round 5
// 33.518 us; speedup vs baseline: 1.1821x; 1.1821x over previous
//
#include <hip/hip_runtime.h>

typedef _Float16 f16x8  __attribute__((ext_vector_type(8)));
typedef float    f32x16 __attribute__((ext_vector_type(16)));

static constexpr int BATCH = 4;
static constexpr int NPTS  = 8192;
static constexpr int NPROB = 2 * BATCH;       // (batch, direction) = 8
static constexpr int RR    = 8;               // ref chunks per problem
static constexpr int RBLK  = NPTS / RR;       // 1024 refs staged per block (16 KB)
static constexpr int TPB   = 256;             // 4 waves
static constexpr int WQ    = 32;              // queries per wave (MFMA cols)
static constexpr int QBLK  = (TPB / 64) * WQ; // 128 queries per block
static constexpr int NQB   = NPTS / QBLK;     // 64 query tiles

__device__ __forceinline__ unsigned packh2(_Float16 lo, _Float16 hi) {
    union { _Float16 h[2]; unsigned u; } v;
    v.h[0] = lo; v.h[1] = hi;
    return v.u;
}

// ---------------- pass 1: per-(qtile, refchunk, prob) partial NN min via MFMA ----------------
__global__ __launch_bounds__(TPB) void cd_pass1(const float* __restrict__ gen,
                                                const float* __restrict__ train,
                                                float* __restrict__ pmin,
                                                unsigned long long* __restrict__ acc,
                                                unsigned* __restrict__ cnt) {
    __shared__ uint4 rA[RBLK];                // 16 KB packed refs (order-scrambled: min-safe)
    const int qb = blockIdx.x, rr = blockIdx.y, prob = blockIdx.z;
    if (qb == 0 && rr == 0 && prob == 0 && threadIdx.x == 0) { *acc = 0ull; *cnt = 0u; }
    const int b = prob >> 1, dir = prob & 1;
    const float* qbase = (dir == 0 ? gen : train) + (size_t)b * NPTS * 3;
    const float* rbase = (dir == 0 ? train : gen) + (size_t)b * NPTS * 3;
    const int lane = threadIdx.x & 63, wave = threadIdx.x >> 6;

    // Stage+pack: thread t loads 4 consecutive points (12 floats, float4-aligned),
    // writes TRANSPOSED rA[i*256+t] -> consecutive lanes hit consecutive 16B slots
    // (conflict-free ds_write_b128). Point order in LDS is permuted - fine for min.
    {
        const float4* s4 = (const float4*)(rbase + rr * (RBLK * 3)) + threadIdx.x * 3;
        const float4 v0 = s4[0], v1 = s4[1], v2 = s4[2];
        const float px[4] = {v0.x, v0.w, v1.z, v2.y};
        const float py[4] = {v0.y, v1.x, v1.w, v2.z};
        const float pz[4] = {v0.z, v1.y, v2.x, v2.w};
        #pragma unroll
        for (int i = 0; i < 4; ++i) {
            const _Float16 hx = (_Float16)px[i], hy = (_Float16)py[i], hz = (_Float16)pz[i];
            const float xr = (float)hx, yr = (float)hy, zr = (float)hz;   // exact
            const float yy = fmaf(xr, xr, fmaf(yr, yr, zr * zr));
            const _Float16 yh = (_Float16)yy;
            const _Float16 yl = (_Float16)(yy - (float)yh);               // hi/lo split
            rA[i * TPB + threadIdx.x] =
                make_uint4(packh2((_Float16)(-2.0f * xr), (_Float16)(-2.0f * yr)),
                           packh2((_Float16)(-2.0f * zr), yh),
                           packh2(yl, (_Float16)0.0f), 0u);
        }
    }

    // Query fragment: 32 queries/wave, B k-vec = [qx,qy,qz,1,1,0,0,0]; lanes>=32 zero
    const int qid = qb * QBLK + wave * WQ + (lane & 31);
    float qq = 0.0f;
    union { uint4 u; f16x8 h; } B;
    B.u = make_uint4(0u, 0u, 0u, 0u);
    if (lane < 32) {
        const float qx = qbase[qid*3+0], qy = qbase[qid*3+1], qz = qbase[qid*3+2];
        const _Float16 hx = (_Float16)qx, hy = (_Float16)qy, hz = (_Float16)qz;
        const float xr = (float)hx, yr = (float)hy, zr = (float)hz;
        qq  = fmaf(xr, xr, fmaf(yr, yr, zr * zr));
        B.u = make_uint4(packh2(hx, hy),
                         packh2(hz, (_Float16)0.0f) | 0x3C000000u,  // k3 = 1.0
                         0x3C00u, 0u);                               // k4 = 1.0
    }
    __syncthreads();

    // 32 tiles: 1 ds_read_b128 + 1 MFMA + 8 min3 (two independent chains)
    float mA = 3.4e38f, mB = 3.4e38f;
    const int c = lane & 31;
    const f32x16 zc = {};
    #pragma unroll 8
    for (int t = 0; t < RBLK / 32; ++t) {
        union { uint4 u; f16x8 h; } A;
        A.u = rA[t * 32 + c];
        f32x16 d = __builtin_amdgcn_mfma_f32_32x32x16_f16(A.h, B.h, zc, 0, 0, 0);
        mA = fminf(fminf(d[0],  d[1]),  mA);
        mA = fminf(fminf(d[2],  d[3]),  mA);
        mA = fminf(fminf(d[4],  d[5]),  mA);
        mA = fminf(fminf(d[6],  d[7]),  mA);
        mB = fminf(fminf(d[8],  d[9]),  mB);
        mB = fminf(fminf(d[10], d[11]), mB);
        mB = fminf(fminf(d[12], d[13]), mB);
        mB = fminf(fminf(d[14], d[15]), mB);
    }
    float m = fminf(mA, mB);
    m = fminf(m, __shfl_xor(m, 32));          // fold the two 16-row halves
    if (lane < 32)
        pmin[((size_t)prob * RR + rr) * NPTS + qid] = m + qq;  // plain store, no atomics
}

// ---------------- pass 2: fold RR partial mins, clamp, deterministic global sum ----------------
__global__ __launch_bounds__(1024) void cd_pass2(const float* __restrict__ pmin,
                                                 unsigned long long* __restrict__ acc,
                                                 unsigned* __restrict__ cnt,
                                                 float* __restrict__ out) {
    const int g = blockIdx.x * 1024 + threadIdx.x;   // 64 blocks x 1024 = 65536 queries
    const int prob = g >> 13, qid = g & (NPTS - 1);
    const float* p = pmin + (size_t)prob * RR * NPTS + qid;
    float m = p[0];
    #pragma unroll
    for (int r = 1; r < RR; ++r) m = fminf(m, p[(size_t)r * NPTS]);
    float d = fmaxf(m, 0.0f);

    #pragma unroll
    for (int off = 32; off >= 1; off >>= 1) d += __shfl_xor(d, off);
    __shared__ float w[16];
    const int wave = threadIdx.x >> 6, lane = threadIdx.x & 63;
    if (lane == 0) w[wave] = d;
    __syncthreads();
    if (threadIdx.x == 0) {
        float t = 0.0f;
        #pragma unroll
        for (int i = 0; i < 16; ++i) t += w[i];
        // fixed-point (2^30) integer add: order-independent -> deterministic
        unsigned long long q = (unsigned long long)((double)t * 1073741824.0 + 0.5);
        atomicAdd(acc, q);
        __threadfence();
        unsigned old = atomicAdd(cnt, 1u);
        if (old == gridDim.x - 1) {           // last block finalizes
            unsigned long long v = atomicAdd(acc, 0ull);   // coherent read via RMW
            out[0] = (float)((double)v * (1.0 / 1073741824.0) * (0.5 / BATCH));
        }
    }
}

extern "C" void kernel_launch(void* const* d_in, const int* in_sizes, int n_in,
                              void* d_out, int out_size, void* d_ws, size_t ws_size,
                              hipStream_t stream) {
    const float* gen   = (const float*)d_in[0];   // [4,8192,3] f32
    const float* train = (const float*)d_in[1];   // [4,8192,3] f32
    char* ws = (char*)d_ws;
    float* pmin = (float*)ws;                                  // 2 MB partial mins
    unsigned long long* acc = (unsigned long long*)(ws + 0x200000);
    unsigned* cnt = (unsigned*)(ws + 0x200008);
    float* out = (float*)d_out;

    cd_pass1<<<dim3(NQB, RR, NPROB), TPB, 0, stream>>>(gen, train, pmin, acc, cnt);
    cd_pass2<<<64, 1024, 0, stream>>>(pmin, acc, cnt, out);
}

// Round 6
// 24.531 us; speedup vs baseline: 1.6152x; 1.3664x over previous
//
#include <hip/hip_runtime.h>

typedef _Float16 f16x8  __attribute__((ext_vector_type(8)));
typedef float    f32x16 __attribute__((ext_vector_type(16)));

static constexpr int BATCH = 4;
static constexpr int NPTS  = 8192;
static constexpr int NPROB = 2 * BATCH;       // (batch, direction) = 8
static constexpr int RR    = 8;               // ref chunks per problem
static constexpr int RBLK  = NPTS / RR;       // 1024 refs staged per block (16 KB)
static constexpr int TPB   = 256;             // 4 waves
static constexpr int WQ    = 64;              // queries per wave (2 MFMA col-groups)
static constexpr int QBLK  = (TPB / 64) * WQ; // 256 queries per block
static constexpr int NQB   = NPTS / QBLK;     // 32 query tiles

__device__ __forceinline__ unsigned packh2(_Float16 lo, _Float16 hi) {
    union { _Float16 h[2]; unsigned u; } v;
    v.h[0] = lo; v.h[1] = hi;
    return v.u;
}

// ---------------- pass 1: per-(qtile, refchunk, prob) partial NN min via MFMA ----------------
__global__ __launch_bounds__(TPB, 6) void cd_pass1(const float* __restrict__ gen,
                                                   const float* __restrict__ train,
                                                   float* __restrict__ pmin,
                                                   unsigned long long* __restrict__ acc,
                                                   unsigned* __restrict__ cnt) {
    __shared__ uint4 rA[RBLK];                // 16 KB packed refs (order-scrambled: min-safe)
    const int qb = blockIdx.x, rr = blockIdx.y, prob = blockIdx.z;
    if (qb == 0 && rr == 0 && prob == 0 && threadIdx.x == 0) { *acc = 0ull; *cnt = 0u; }
    const int b = prob >> 1, dir = prob & 1;
    const float* qbase = (dir == 0 ? gen : train) + (size_t)b * NPTS * 3;
    const float* rbase = (dir == 0 ? train : gen) + (size_t)b * NPTS * 3;
    const int lane = threadIdx.x & 63, wave = threadIdx.x >> 6;

    // Stage+pack: thread t loads 4 consecutive points (12 floats, float4-aligned),
    // writes TRANSPOSED rA[i*256+t] -> consecutive lanes hit consecutive 16B slots
    // (conflict-free ds_write_b128). Point order in LDS is permuted - fine for min.
    {
        const float4* s4 = (const float4*)(rbase + rr * (RBLK * 3)) + threadIdx.x * 3;
        const float4 v0 = s4[0], v1 = s4[1], v2 = s4[2];
        const float px[4] = {v0.x, v0.w, v1.z, v2.y};
        const float py[4] = {v0.y, v1.x, v1.w, v2.z};
        const float pz[4] = {v0.z, v1.y, v2.x, v2.w};
        #pragma unroll
        for (int i = 0; i < 4; ++i) {
            const _Float16 hx = (_Float16)px[i], hy = (_Float16)py[i], hz = (_Float16)pz[i];
            const float xr = (float)hx, yr = (float)hy, zr = (float)hz;   // exact
            const float yy = fmaf(xr, xr, fmaf(yr, yr, zr * zr));
            const _Float16 yh = (_Float16)yy;
            const _Float16 yl = (_Float16)(yy - (float)yh);               // hi/lo split
            rA[i * TPB + threadIdx.x] =
                make_uint4(packh2((_Float16)(-2.0f * xr), (_Float16)(-2.0f * yr)),
                           packh2((_Float16)(-2.0f * zr), yh),
                           packh2(yl, (_Float16)0.0f), 0u);
        }
    }

    // Two query fragments per wave: cols = 32 queries each; B k-vec = [qx,qy,qz,1,1,0,0,0]
    const int qid0 = qb * QBLK + wave * WQ + (lane & 31);
    const int qid1 = qid0 + 32;
    float qq0 = 0.0f, qq1 = 0.0f;
    union { uint4 u; f16x8 h; } B0, B1;
    B0.u = make_uint4(0u, 0u, 0u, 0u);
    B1.u = make_uint4(0u, 0u, 0u, 0u);
    if (lane < 32) {
        {
            const float qx = qbase[qid0*3+0], qy = qbase[qid0*3+1], qz = qbase[qid0*3+2];
            const _Float16 hx = (_Float16)qx, hy = (_Float16)qy, hz = (_Float16)qz;
            const float xr = (float)hx, yr = (float)hy, zr = (float)hz;
            qq0  = fmaf(xr, xr, fmaf(yr, yr, zr * zr));
            B0.u = make_uint4(packh2(hx, hy),
                              packh2(hz, (_Float16)0.0f) | 0x3C000000u, 0x3C00u, 0u);
        }
        {
            const float qx = qbase[qid1*3+0], qy = qbase[qid1*3+1], qz = qbase[qid1*3+2];
            const _Float16 hx = (_Float16)qx, hy = (_Float16)qy, hz = (_Float16)qz;
            const float xr = (float)hx, yr = (float)hy, zr = (float)hz;
            qq1  = fmaf(xr, xr, fmaf(yr, yr, zr * zr));
            B1.u = make_uint4(packh2(hx, hy),
                              packh2(hz, (_Float16)0.0f) | 0x3C000000u, 0x3C00u, 0u);
        }
    }
    __syncthreads();

    // 32 tiles: 1 ds_read_b128 + 2 MFMA + 16 min3 (four independent accum chains)
    float m0A = 3.4e38f, m0B = 3.4e38f, m1A = 3.4e38f, m1B = 3.4e38f;
    const int c = lane & 31;
    const f32x16 zc = {};
    #pragma unroll 4
    for (int t = 0; t < RBLK / 32; ++t) {
        union { uint4 u; f16x8 h; } A;
        A.u = rA[t * 32 + c];
        f32x16 d0 = __builtin_amdgcn_mfma_f32_32x32x16_f16(A.h, B0.h, zc, 0, 0, 0);
        f32x16 d1 = __builtin_amdgcn_mfma_f32_32x32x16_f16(A.h, B1.h, zc, 0, 0, 0);
        m0A = fminf(fminf(d0[0],  d0[1]),  m0A);
        m0A = fminf(fminf(d0[2],  d0[3]),  m0A);
        m0A = fminf(fminf(d0[4],  d0[5]),  m0A);
        m0A = fminf(fminf(d0[6],  d0[7]),  m0A);
        m0B = fminf(fminf(d0[8],  d0[9]),  m0B);
        m0B = fminf(fminf(d0[10], d0[11]), m0B);
        m0B = fminf(fminf(d0[12], d0[13]), m0B);
        m0B = fminf(fminf(d0[14], d0[15]), m0B);
        m1A = fminf(fminf(d1[0],  d1[1]),  m1A);
        m1A = fminf(fminf(d1[2],  d1[3]),  m1A);
        m1A = fminf(fminf(d1[4],  d1[5]),  m1A);
        m1A = fminf(fminf(d1[6],  d1[7]),  m1A);
        m1B = fminf(fminf(d1[8],  d1[9]),  m1B);
        m1B = fminf(fminf(d1[10], d1[11]), m1B);
        m1B = fminf(fminf(d1[12], d1[13]), m1B);
        m1B = fminf(fminf(d1[14], d1[15]), m1B);
    }
    float m0 = fminf(m0A, m0B);
    float m1 = fminf(m1A, m1B);
    m0 = fminf(m0, __shfl_xor(m0, 32));       // fold the two 16-row halves
    m1 = fminf(m1, __shfl_xor(m1, 32));
    if (lane < 32) {
        float* dst = pmin + ((size_t)prob * RR + rr) * NPTS;
        dst[qid0] = m0 + qq0;                 // plain stores, no atomics
        dst[qid1] = m1 + qq1;
    }
}

// ---------------- pass 2: fold RR partial mins, clamp, deterministic global sum ----------------
__global__ __launch_bounds__(1024) void cd_pass2(const float* __restrict__ pmin,
                                                 unsigned long long* __restrict__ acc,
                                                 unsigned* __restrict__ cnt,
                                                 float* __restrict__ out) {
    const int g = blockIdx.x * 1024 + threadIdx.x;   // 64 blocks x 1024 = 65536 queries
    const int prob = g >> 13, qid = g & (NPTS - 1);
    const float* p = pmin + (size_t)prob * RR * NPTS + qid;
    float m = p[0];
    #pragma unroll
    for (int r = 1; r < RR; ++r) m = fminf(m, p[(size_t)r * NPTS]);
    float d = fmaxf(m, 0.0f);

    #pragma unroll
    for (int off = 32; off >= 1; off >>= 1) d += __shfl_xor(d, off);
    __shared__ float w[16];
    const int wave = threadIdx.x >> 6, lane = threadIdx.x & 63;
    if (lane == 0) w[wave] = d;
    __syncthreads();
    if (threadIdx.x == 0) {
        float t = 0.0f;
        #pragma unroll
        for (int i = 0; i < 16; ++i) t += w[i];
        // fixed-point (2^30) integer add: order-independent -> deterministic
        unsigned long long q = (unsigned long long)((double)t * 1073741824.0 + 0.5);
        atomicAdd(acc, q);
        __threadfence();
        unsigned old = atomicAdd(cnt, 1u);
        if (old == gridDim.x - 1) {           // last block finalizes
            unsigned long long v = atomicAdd(acc, 0ull);   // coherent read via RMW
            out[0] = (float)((double)v * (1.0 / 1073741824.0) * (0.5 / BATCH));
        }
    }
}

extern "C" void kernel_launch(void* const* d_in, const int* in_sizes, int n_in,
                              void* d_out, int out_size, void* d_ws, size_t ws_size,
                              hipStream_t stream) {
    const float* gen   = (const float*)d_in[0];   // [4,8192,3] f32
    const float* train = (const float*)d_in[1];   // [4,8192,3] f32
    char* ws = (char*)d_ws;
    float* pmin = (float*)ws;                                  // 2 MB partial mins
    unsigned long long* acc = (unsigned long long*)(ws + 0x200000);
    unsigned* cnt = (unsigned*)(ws + 0x200008);
    float* out = (float*)d_out;

    cd_pass1<<<dim3(NQB, RR, NPROB), TPB, 0, stream>>>(gen, train, pmin, acc, cnt);
    cd_pass2<<<64, 1024, 0, stream>>>(pmin, acc, cnt, out);
}

// Round 8
// 24.296 us; speedup vs baseline: 1.6308x; 1.0097x over previous
//
#include <hip/hip_runtime.h>

typedef _Float16 f16x8  __attribute__((ext_vector_type(8)));
typedef float    f32x16 __attribute__((ext_vector_type(16)));

static constexpr int BATCH = 4;
static constexpr int NPTS  = 8192;
static constexpr int NPROB = 2 * BATCH;       // (batch, direction) = 8
static constexpr int RR    = 8;               // ref chunks per problem
static constexpr int RBLK  = NPTS / RR;       // 1024 refs staged per block (16 KB)
static constexpr int TPB   = 256;             // 4 waves
static constexpr int WQ    = 128;             // queries per wave (4 MFMA col-groups)
static constexpr int QBLK  = (TPB / 64) * WQ; // 512 queries per block
static constexpr int NQB   = NPTS / QBLK;     // 16 query tiles

__device__ __forceinline__ unsigned packh2(_Float16 lo, _Float16 hi) {
    union { _Float16 h[2]; unsigned u; } v;
    v.h[0] = lo; v.h[1] = hi;
    return v.u;
}

// ---------------- pass 1: per-(qtile, refchunk, prob) partial NN min via MFMA ----------------
__global__ __launch_bounds__(TPB, 4) void cd_pass1(const float* __restrict__ gen,
                                                   const float* __restrict__ train,
                                                   float* __restrict__ pmin,
                                                   unsigned long long* __restrict__ acc,
                                                   unsigned* __restrict__ cnt) {
    __shared__ uint4 rA[RBLK];                // 16 KB packed refs (order-scrambled: min-safe)
    const int qb = blockIdx.x, rr = blockIdx.y, prob = blockIdx.z;
    if (qb == 0 && rr == 0 && prob == 0 && threadIdx.x == 0) { *acc = 0ull; *cnt = 0u; }
    const int b = prob >> 1, dir = prob & 1;
    const float* qbase = (dir == 0 ? gen : train) + (size_t)b * NPTS * 3;
    const float* rbase = (dir == 0 ? train : gen) + (size_t)b * NPTS * 3;
    const int lane = threadIdx.x & 63, wave = threadIdx.x >> 6;

    // Stage+pack: thread t loads 4 consecutive points (12 floats, float4-aligned),
    // writes TRANSPOSED rA[i*256+t] -> consecutive lanes hit consecutive 16B slots
    // (conflict-free ds_write_b128). Point order in LDS is permuted - fine for min.
    {
        const float4* s4 = (const float4*)(rbase + rr * (RBLK * 3)) + threadIdx.x * 3;
        const float4 v0 = s4[0], v1 = s4[1], v2 = s4[2];
        const float px[4] = {v0.x, v0.w, v1.z, v2.y};
        const float py[4] = {v0.y, v1.x, v1.w, v2.z};
        const float pz[4] = {v0.z, v1.y, v2.x, v2.w};
        #pragma unroll
        for (int i = 0; i < 4; ++i) {
            const _Float16 hx = (_Float16)px[i], hy = (_Float16)py[i], hz = (_Float16)pz[i];
            const float xr = (float)hx, yr = (float)hy, zr = (float)hz;   // exact
            const float yy = fmaf(xr, xr, fmaf(yr, yr, zr * zr));
            const _Float16 yh = (_Float16)yy;
            const _Float16 yl = (_Float16)(yy - (float)yh);               // hi/lo split
            rA[i * TPB + threadIdx.x] =
                make_uint4(packh2((_Float16)(-2.0f * xr), (_Float16)(-2.0f * yr)),
                           packh2((_Float16)(-2.0f * zr), yh),
                           packh2(yl, (_Float16)0.0f), 0u);
        }
    }

    // Four query fragments per wave: 32 queries each; B k-vec = [qx,qy,qz,1,1,0,0,0]
    const int qid0 = qb * QBLK + wave * WQ + (lane & 31);
    const int qid1 = qid0 + 32, qid2 = qid0 + 64, qid3 = qid0 + 96;
    float qq0 = 0.0f, qq1 = 0.0f, qq2 = 0.0f, qq3 = 0.0f;
    union { uint4 u; f16x8 h; } B0, B1, B2, B3;
    B0.u = make_uint4(0u, 0u, 0u, 0u);
    B1.u = make_uint4(0u, 0u, 0u, 0u);
    B2.u = make_uint4(0u, 0u, 0u, 0u);
    B3.u = make_uint4(0u, 0u, 0u, 0u);
    if (lane < 32) {
        {
            const float qx = qbase[qid0*3+0], qy = qbase[qid0*3+1], qz = qbase[qid0*3+2];
            const _Float16 hx = (_Float16)qx, hy = (_Float16)qy, hz = (_Float16)qz;
            const float xr = (float)hx, yr = (float)hy, zr = (float)hz;
            qq0  = fmaf(xr, xr, fmaf(yr, yr, zr * zr));
            B0.u = make_uint4(packh2(hx, hy),
                              packh2(hz, (_Float16)0.0f) | 0x3C000000u, 0x3C00u, 0u);
        }
        {
            const float qx = qbase[qid1*3+0], qy = qbase[qid1*3+1], qz = qbase[qid1*3+2];
            const _Float16 hx = (_Float16)qx, hy = (_Float16)qy, hz = (_Float16)qz;
            const float xr = (float)hx, yr = (float)hy, zr = (float)hz;
            qq1  = fmaf(xr, xr, fmaf(yr, yr, zr * zr));
            B1.u = make_uint4(packh2(hx, hy),
                              packh2(hz, (_Float16)0.0f) | 0x3C000000u, 0x3C00u, 0u);
        }
        {
            const float qx = qbase[qid2*3+0], qy = qbase[qid2*3+1], qz = qbase[qid2*3+2];
            const _Float16 hx = (_Float16)qx, hy = (_Float16)qy, hz = (_Float16)qz;
            const float xr = (float)hx, yr = (float)hy, zr = (float)hz;
            qq2  = fmaf(xr, xr, fmaf(yr, yr, zr * zr));
            B2.u = make_uint4(packh2(hx, hy),
                              packh2(hz, (_Float16)0.0f) | 0x3C000000u, 0x3C00u, 0u);
        }
        {
            const float qx = qbase[qid3*3+0], qy = qbase[qid3*3+1], qz = qbase[qid3*3+2];
            const _Float16 hx = (_Float16)qx, hy = (_Float16)qy, hz = (_Float16)qz;
            const float xr = (float)hx, yr = (float)hy, zr = (float)hz;
            qq3  = fmaf(xr, xr, fmaf(yr, yr, zr * zr));
            B3.u = make_uint4(packh2(hx, hy),
                              packh2(hz, (_Float16)0.0f) | 0x3C000000u, 0x3C00u, 0u);
        }
    }
    __syncthreads();

    // 32 tiles: 1 ds_read_b128 feeds 4 MFMAs; fminf-pair folds (compiler fuses to v_min3)
    float m0A = 3.4e38f, m0B = 3.4e38f, m1A = 3.4e38f, m1B = 3.4e38f;
    float m2A = 3.4e38f, m2B = 3.4e38f, m3A = 3.4e38f, m3B = 3.4e38f;
    const int c = lane & 31;
    const f32x16 zc = {};
    #pragma unroll 4
    for (int t = 0; t < RBLK / 32; ++t) {
        union { uint4 u; f16x8 h; } A;
        A.u = rA[t * 32 + c];
        f32x16 d0 = __builtin_amdgcn_mfma_f32_32x32x16_f16(A.h, B0.h, zc, 0, 0, 0);
        f32x16 d1 = __builtin_amdgcn_mfma_f32_32x32x16_f16(A.h, B1.h, zc, 0, 0, 0);
        f32x16 d2 = __builtin_amdgcn_mfma_f32_32x32x16_f16(A.h, B2.h, zc, 0, 0, 0);
        f32x16 d3 = __builtin_amdgcn_mfma_f32_32x32x16_f16(A.h, B3.h, zc, 0, 0, 0);
        m0A = fminf(fminf(d0[0],  d0[1]),  m0A);
        m0A = fminf(fminf(d0[2],  d0[3]),  m0A);
        m0A = fminf(fminf(d0[4],  d0[5]),  m0A);
        m0A = fminf(fminf(d0[6],  d0[7]),  m0A);
        m0B = fminf(fminf(d0[8],  d0[9]),  m0B);
        m0B = fminf(fminf(d0[10], d0[11]), m0B);
        m0B = fminf(fminf(d0[12], d0[13]), m0B);
        m0B = fminf(fminf(d0[14], d0[15]), m0B);
        m1A = fminf(fminf(d1[0],  d1[1]),  m1A);
        m1A = fminf(fminf(d1[2],  d1[3]),  m1A);
        m1A = fminf(fminf(d1[4],  d1[5]),  m1A);
        m1A = fminf(fminf(d1[6],  d1[7]),  m1A);
        m1B = fminf(fminf(d1[8],  d1[9]),  m1B);
        m1B = fminf(fminf(d1[10], d1[11]), m1B);
        m1B = fminf(fminf(d1[12], d1[13]), m1B);
        m1B = fminf(fminf(d1[14], d1[15]), m1B);
        m2A = fminf(fminf(d2[0],  d2[1]),  m2A);
        m2A = fminf(fminf(d2[2],  d2[3]),  m2A);
        m2A = fminf(fminf(d2[4],  d2[5]),  m2A);
        m2A = fminf(fminf(d2[6],  d2[7]),  m2A);
        m2B = fminf(fminf(d2[8],  d2[9]),  m2B);
        m2B = fminf(fminf(d2[10], d2[11]), m2B);
        m2B = fminf(fminf(d2[12], d2[13]), m2B);
        m2B = fminf(fminf(d2[14], d2[15]), m2B);
        m3A = fminf(fminf(d3[0],  d3[1]),  m3A);
        m3A = fminf(fminf(d3[2],  d3[3]),  m3A);
        m3A = fminf(fminf(d3[4],  d3[5]),  m3A);
        m3A = fminf(fminf(d3[6],  d3[7]),  m3A);
        m3B = fminf(fminf(d3[8],  d3[9]),  m3B);
        m3B = fminf(fminf(d3[10], d3[11]), m3B);
        m3B = fminf(fminf(d3[12], d3[13]), m3B);
        m3B = fminf(fminf(d3[14], d3[15]), m3B);
    }
    float m0 = fminf(m0A, m0B);
    float m1 = fminf(m1A, m1B);
    float m2 = fminf(m2A, m2B);
    float m3 = fminf(m3A, m3B);
    m0 = fminf(m0, __shfl_xor(m0, 32));       // fold the two 16-row halves
    m1 = fminf(m1, __shfl_xor(m1, 32));
    m2 = fminf(m2, __shfl_xor(m2, 32));
    m3 = fminf(m3, __shfl_xor(m3, 32));
    if (lane < 32) {
        float* dst = pmin + ((size_t)prob * RR + rr) * NPTS;
        dst[qid0] = m0 + qq0;                 // plain stores, no atomics
        dst[qid1] = m1 + qq1;
        dst[qid2] = m2 + qq2;
        dst[qid3] = m3 + qq3;
    }
}

// ---------------- pass 2: fold RR partial mins, clamp, deterministic global sum ----------------
__global__ __launch_bounds__(1024) void cd_pass2(const float* __restrict__ pmin,
                                                 unsigned long long* __restrict__ acc,
                                                 unsigned* __restrict__ cnt,
                                                 float* __restrict__ out) {
    const int g = blockIdx.x * 1024 + threadIdx.x;   // 64 blocks x 1024 = 65536 queries
    const int prob = g >> 13, qid = g & (NPTS - 1);
    const float* p = pmin + (size_t)prob * RR * NPTS + qid;
    float m = p[0];
    #pragma unroll
    for (int r = 1; r < RR; ++r) m = fminf(m, p[(size_t)r * NPTS]);
    float d = fmaxf(m, 0.0f);

    #pragma unroll
    for (int off = 32; off >= 1; off >>= 1) d += __shfl_xor(d, off);
    __shared__ float w[16];
    const int wave = threadIdx.x >> 6, lane = threadIdx.x & 63;
    if (lane == 0) w[wave] = d;
    __syncthreads();
    if (threadIdx.x == 0) {
        float t = 0.0f;
        #pragma unroll
        for (int i = 0; i < 16; ++i) t += w[i];
        // fixed-point (2^30) integer add: order-independent -> deterministic
        unsigned long long q = (unsigned long long)((double)t * 1073741824.0 + 0.5);
        atomicAdd(acc, q);
        __threadfence();
        unsigned old = atomicAdd(cnt, 1u);
        if (old == gridDim.x - 1) {           // last block finalizes
            unsigned long long v = atomicAdd(acc, 0ull);   // coherent read via RMW
            out[0] = (float)((double)v * (1.0 / 1073741824.0) * (0.5 / BATCH));
        }
    }
}

extern "C" void kernel_launch(void* const* d_in, const int* in_sizes, int n_in,
                              void* d_out, int out_size, void* d_ws, size_t ws_size,
                              hipStream_t stream) {
    const float* gen   = (const float*)d_in[0];   // [4,8192,3] f32
    const float* train = (const float*)d_in[1];   // [4,8192,3] f32
    char* ws = (char*)d_ws;
    float* pmin = (float*)ws;                                  // 2 MB partial mins
    unsigned long long* acc = (unsigned long long*)(ws + 0x200000);
    unsigned* cnt = (unsigned*)(ws + 0x200008);
    float* out = (float*)d_out;

    cd_pass1<<<dim3(NQB, RR, NPROB), TPB, 0, stream>>>(gen, train, pmin, acc, cnt);
    cd_pass2<<<64, 1024, 0, stream>>>(pmin, acc, cnt, out);
}